// Round 11
// baseline (221.739 us; speedup 1.0000x reference)
//
#include <hip/hip_runtime.h>
#include <hip/hip_bf16.h>

typedef __attribute__((ext_vector_type(8))) short bf16x8;
typedef __attribute__((ext_vector_type(4))) float f32x4;
typedef unsigned short u16;
typedef unsigned int u32;

#define MFMA16(a,b,c) __builtin_amdgcn_mfma_f32_16x16x32_bf16((a),(b),(c),0,0,0)

#if defined(__has_builtin) && __has_builtin(__builtin_amdgcn_exp2f)
#define EXP2(x) __builtin_amdgcn_exp2f(x)
#else
#define EXP2(x) exp2f(x)
#endif

// softmax scale folded into Q at projection time: (1/32) * log2(e)
#define QSCALE 0.045084220027780106f

__device__ __forceinline__ u16 f2bf(float f) {
  union { float f; unsigned int u; } v; v.f = f;
  unsigned int r = v.u + 0x7FFFu + ((v.u >> 16) & 1u);   // RNE
  return (u16)(r >> 16);
}

__device__ __forceinline__ u32 pkbf(float a, float b) {
  union { __hip_bfloat162 h; u32 u; } cv;
  cv.h = __float22bfloat162_rn(make_float2(a, b));
  return cv.u;
}

// async global->LDS, 16B per lane; LDS dest = wave-uniform base + lane*16
__device__ __forceinline__ void gld16(const void* g, void* l) {
  __builtin_amdgcn_global_load_lds(
      (__attribute__((address_space(1))) void*)(g),
      (__attribute__((address_space(3))) void*)(l), 16, 0, 0);
}

#define SB __builtin_amdgcn_sched_barrier(0);

// ---------------- fused QKV projection GEMM (fp32 in, cast fused) ----------
// Replaces cast_all + bf16 GEMM: A (qu/x) and W (wq/wk/wv) are read as fp32,
// converted in-register (cvt_pk) and ds_written into the SAME swizzled LDS
// layout the verified gld16 path used (identical seg/lseg/row math; only the
// transport changed). Loads for step k+1 are issued right after the
// cvt+write of step k consumes its regs -> in flight across the whole
// compute phase; no vmcnt asm needed (register deps). Raw barriers +
// per-wave lgkmcnt(0) (no __syncthreads vmcnt-drain).
// z=0: Q*(scale*log2e) -> [B,H,N,D]; z=1: K -> [B,H,N,D] (both as C^T);
// z=2: V -> [B,H,D,N'] permuted transposed layout.
__global__ __launch_bounds__(256) void gemm_qkv(
    const float* __restrict__ qu, const float* __restrict__ x,
    const float* __restrict__ wq, const float* __restrict__ wk,
    const float* __restrict__ wv,
    const float* __restrict__ bq, const float* __restrict__ bk,
    const float* __restrict__ bv,
    u16* __restrict__ qhd, u16* __restrict__ khd, u16* __restrict__ vtd)
{
  __shared__ u16 As[128 * 64];
  __shared__ u16 Bs[128 * 64];
  int tid = threadIdx.x, w = tid >> 6, lane = tid & 63;
  int c = lane & 15, quad = lane >> 4;
  int bm = blockIdx.x, bn = blockIdx.y, z = blockIdx.z;
  int wm = w >> 1, wn = w & 1;
  const float* A = (z == 0) ? qu : x;
  const float* W = (z == 0) ? wq : (z == 1) ? wk : wv;
  f32x4 acc[4][4] = {};
  float4 ra[4][2], rb[4][2];

  // per-thread staging geometry (identical to the gld16 path):
  // seg i covers row=seg>>3, phys seg pseg=seg&7, logical k-seg lseg=pseg^(row&7)
#define QLOAD(K0)                                                               \
  {                                                                             \
    _Pragma("unroll") for (int i = 0; i < 4; i++) {                             \
      int seg = i * 256 + w * 64 + lane;                                        \
      int row = seg >> 3, pseg = seg & 7;                                       \
      int lseg = pseg ^ (row & 7);                                              \
      const float* pa = A + (size_t)(bm * 128 + row) * 1024 + (K0) + lseg * 8;  \
      const float* pb = W + (size_t)(bn * 128 + row) * 1024 + (K0) + lseg * 8;  \
      ra[i][0] = *(const float4*)pa; ra[i][1] = *(const float4*)(pa + 4);       \
      rb[i][0] = *(const float4*)pb; rb[i][1] = *(const float4*)(pb + 4);       \
    }                                                                           \
  }

#define QWRITE                                                                  \
  {                                                                             \
    _Pragma("unroll") for (int i = 0; i < 4; i++) {                             \
      int seg = i * 256 + w * 64 + lane;                                        \
      uint4 wa, wb;                                                             \
      wa.x = pkbf(ra[i][0].x, ra[i][0].y); wa.y = pkbf(ra[i][0].z, ra[i][0].w); \
      wa.z = pkbf(ra[i][1].x, ra[i][1].y); wa.w = pkbf(ra[i][1].z, ra[i][1].w); \
      wb.x = pkbf(rb[i][0].x, rb[i][0].y); wb.y = pkbf(rb[i][0].z, rb[i][0].w); \
      wb.z = pkbf(rb[i][1].x, rb[i][1].y); wb.w = pkbf(rb[i][1].z, rb[i][1].w); \
      *(uint4*)&As[seg * 8] = wa;                                               \
      *(uint4*)&Bs[seg * 8] = wb;                                               \
    }                                                                           \
  }

#define QCOMP                                                                   \
  {                                                                             \
    _Pragma("unroll") for (int ks = 0; ks < 2; ks++) {                          \
      bf16x8 af[4], bfr[4];                                                     \
      _Pragma("unroll") for (int mt = 0; mt < 4; mt++) {                        \
        int row = wm * 64 + mt * 16 + c;                                        \
        int cseg = (ks * 4 + quad) ^ (row & 7);                                 \
        af[mt] = *(const bf16x8*)&As[(row * 8 + cseg) * 8];                     \
      }                                                                         \
      _Pragma("unroll") for (int nt = 0; nt < 4; nt++) {                        \
        int row = wn * 64 + nt * 16 + c;                                        \
        int cseg = (ks * 4 + quad) ^ (row & 7);                                 \
        bfr[nt] = *(const bf16x8*)&Bs[(row * 8 + cseg) * 8];                    \
      }                                                                         \
      if (z < 2) {                                                              \
        _Pragma("unroll") for (int ct = 0; ct < 4; ct++)                        \
          _Pragma("unroll") for (int tt = 0; tt < 4; tt++)                      \
            acc[ct][tt] = MFMA16(bfr[ct], af[tt], acc[ct][tt]);                 \
      } else {                                                                  \
        _Pragma("unroll") for (int mt = 0; mt < 4; mt++)                        \
          _Pragma("unroll") for (int nt = 0; nt < 4; nt++)                      \
            acc[mt][nt] = MFMA16(af[mt], bfr[nt], acc[mt][nt]);                 \
      }                                                                         \
    }                                                                           \
  }

  QLOAD(0)
  for (int st = 0; st < 16; st++) {
    QWRITE                                   // waits loads via reg deps
    if (st < 15) QLOAD((st + 1) * 64)        // prefetch; in flight over compute
    SB asm volatile("s_waitcnt lgkmcnt(0)" ::: "memory"); SB
    __builtin_amdgcn_s_barrier(); SB         // all waves' writes visible
    QCOMP
    SB __builtin_amdgcn_s_barrier(); SB      // all reads done before overwrite
  }
#undef QCOMP
#undef QWRITE
#undef QLOAD

  if (z < 2) {
    const float* bias = (z == 0) ? bq : bk;
    u16* dst = (z == 0) ? qhd : khd;
    float sc = (z == 0) ? QSCALE : 1.0f;
    // per-lane bias for 4 consecutive channels per ct (16B-aligned)
    float4 bbs[4];
#pragma unroll
    for (int ct = 0; ct < 4; ct++) {
      float4 b4 = *(const float4*)&bias[bn * 128 + wn * 64 + ct * 16 + quad * 4];
      bbs[ct].x = b4.x * sc; bbs[ct].y = b4.y * sc;
      bbs[ct].z = b4.z * sc; bbs[ct].w = b4.w * sc;
    }
#pragma unroll
    for (int ct = 0; ct < 4; ct++) {
      int ch = bn * 128 + wn * 64 + ct * 16 + quad * 4;
      int h = ch >> 6, d0 = ch & 63;
#pragma unroll
      for (int tt = 0; tt < 4; tt++) {
        int tok = bm * 128 + wm * 64 + tt * 16 + c;
        int b = tok >> 11, n = tok & 2047;
        float v0 = fmaf(acc[ct][tt][0], sc, bbs[ct].x);
        float v1 = fmaf(acc[ct][tt][1], sc, bbs[ct].y);
        float v2 = fmaf(acc[ct][tt][2], sc, bbs[ct].z);
        float v3 = fmaf(acc[ct][tt][3], sc, bbs[ct].w);
        uint2 pk; pk.x = pkbf(v0, v1); pk.y = pkbf(v2, v3);
        *(uint2*)&dst[((size_t)(b * 16 + h) * 2048 + n) * 64 + d0] = pk;
      }
    }
  } else {
    float bval[4];
#pragma unroll
    for (int nt = 0; nt < 4; nt++)
      bval[nt] = bv[bn * 128 + wn * 64 + nt * 16 + c];
#pragma unroll
    for (int mt = 0; mt < 4; mt++) {
      int tokl = (mt & 2) * 16 + quad * 8 + (mt & 1) * 4;   // permuted, +j
      int tok = bm * 128 + wm * 64 + tokl;
      int b = tok >> 11, np = tok & 2047;
#pragma unroll
      for (int nt = 0; nt < 4; nt++) {
        int ch = bn * 128 + wn * 64 + nt * 16 + c;
        int h = ch >> 6, d = ch & 63;
        float v0 = acc[mt][nt][0] + bval[nt];
        float v1 = acc[mt][nt][1] + bval[nt];
        float v2 = acc[mt][nt][2] + bval[nt];
        float v3 = acc[mt][nt][3] + bval[nt];
        uint2 pk; pk.x = pkbf(v0, v1); pk.y = pkbf(v2, v3);
        *(uint2*)&vtd[((size_t)(b * 16 + h) * 64 + d) * 2048 + np] = pk;
      }
    }
  }
}

// ---------------- attention v12: token-split waves, private LDS dbuf ------
// (R7/R10-verified ~50 us version, unchanged)
__global__ __launch_bounds__(128, 2) void attn(
    const u16* __restrict__ qh, const u16* __restrict__ kh,
    const u16* __restrict__ vt, u16* __restrict__ ot)
{
  __shared__ u16 KL[2][2][32 * 64];   // [wave][buf] K tile [32 tok][64 d], 4 KB
  __shared__ u16 VL[2][2][64 * 32];   // [wave][buf] V tile [64 d][32 tok'], 4 KB
  __shared__ float CL[64];            // wave-1 L partials
  int tid = threadIdx.x, w = tid >> 6, lane = tid & 63;
  int c = lane & 15, quad = lane >> 4;
  int bh = blockIdx.x, qt = blockIdx.y;

  // Q B-frags in registers: 64 q shared by both waves
  const u16* qp = qh + ((size_t)bh * 2048 + qt * 64) * 64;
  bf16x8 Qf[4][2];
#pragma unroll
  for (int q2 = 0; q2 < 4; q2++)
#pragma unroll
    for (int ks = 0; ks < 2; ks++)
      Qf[q2][ks] = *(const bf16x8*)(qp + (size_t)(q2 * 16 + c) * 64 + ks * 32 + quad * 8);

  // K staging: 4 loads; load i covers token-row i*8+(lane>>3), seg (lane&7)^(row&7)
  int kro = lane >> 3;                    // 0..7
  int ksw = ((lane & 7) ^ (kro & 7)) * 8;
  const u16* kg = kh + (size_t)bh * 131072 + (size_t)w * 65536 + kro * 64 + ksw;
  // V staging: 4 loads; load i covers d-row i*16+(lane>>2), seg (lane&3)^(row&3)
  int vro = lane >> 2;                    // 0..15
  int vsw = ((lane & 3) ^ (vro & 3)) * 8;
  const u16* vg = vt + (size_t)bh * 131072 + (size_t)vro * 2048 + w * 1024 + vsw;

  // fragment read offsets (swizzled)
  int off0 = c * 64 + ((quad) ^ (c & 7)) * 8;        // K ks=0 (d 0..31)
  int off1 = c * 64 + ((4 + quad) ^ (c & 7)) * 8;    // K ks=1 (d 32..63)
  int offV = c * 32 + ((quad ^ (c & 3)) & 3) * 8;    // V (+ dt*512)

#define STAGE(B)                                                                \
  {                                                                             \
    gld16(kg,          &KL[w][B][0]);                                           \
    gld16(kg + 512,    &KL[w][B][512]);                                         \
    gld16(kg + 1024,   &KL[w][B][1024]);                                        \
    gld16(kg + 1536,   &KL[w][B][1536]);                                        \
    gld16(vg,          &VL[w][B][0]);                                           \
    gld16(vg + 32768,  &VL[w][B][512]);                                         \
    gld16(vg + 65536,  &VL[w][B][1024]);                                        \
    gld16(vg + 98304,  &VL[w][B][1536]);                                        \
    kg += 2048; vg += 32;                                                       \
  }

  f32x4 O[4][4] = {};
  f32x4 Lacc[4] = {};
  bf16x8 vone;
#pragma unroll
  for (int j = 0; j < 8; j++) vone[j] = (short)0x3F80;   // bf16 1.0

  // per iter: [lgkm(0)] protect buf about to be overwritten; stage t+1;
  // counted vmcnt(8) -> tile t's 8 loads complete; compute tile t.
#define ITER(PH, PREF)                                                          \
  {                                                                             \
    asm volatile("s_waitcnt lgkmcnt(0)" ::: "memory");                          \
    __builtin_amdgcn_sched_barrier(0);                                          \
    if (PREF) STAGE(PH ^ 1)                                                     \
    if (PREF) { asm volatile("s_waitcnt vmcnt(8)" ::: "memory"); }              \
    else      { asm volatile("s_waitcnt vmcnt(0)" ::: "memory"); }              \
    __builtin_amdgcn_sched_barrier(0);                                          \
    const u16* Ks = KL[w][PH];                                                  \
    const u16* Vs = VL[w][PH];                                                  \
    bf16x8 Kf[2][2];                                                            \
    Kf[0][0] = *(const bf16x8*)&Ks[off0];                                       \
    Kf[0][1] = *(const bf16x8*)&Ks[off1];                                       \
    Kf[1][0] = *(const bf16x8*)&Ks[off0 + 1024];                                \
    Kf[1][1] = *(const bf16x8*)&Ks[off1 + 1024];                                \
    f32x4 S[4][2] = {};                                                         \
    _Pragma("unroll") for (int q2 = 0; q2 < 4; q2++)                            \
      _Pragma("unroll") for (int nt = 0; nt < 2; nt++) {                        \
        S[q2][nt] = MFMA16(Kf[nt][0], Qf[q2][0], S[q2][nt]);                    \
        S[q2][nt] = MFMA16(Kf[nt][1], Qf[q2][1], S[q2][nt]);                    \
      }                                                                         \
    bf16x8 pa[4];                                                               \
    _Pragma("unroll") for (int q2 = 0; q2 < 4; q2++) {                          \
      float e0 = EXP2(S[q2][0][0]), e1 = EXP2(S[q2][0][1]);                     \
      float e2 = EXP2(S[q2][0][2]), e3 = EXP2(S[q2][0][3]);                     \
      float e4 = EXP2(S[q2][1][0]), e5 = EXP2(S[q2][1][1]);                     \
      float e6 = EXP2(S[q2][1][2]), e7 = EXP2(S[q2][1][3]);                     \
      union { uint4 u; bf16x8 v; } cv;                                          \
      cv.u.x = pkbf(e0, e1); cv.u.y = pkbf(e2, e3);                             \
      cv.u.z = pkbf(e4, e5); cv.u.w = pkbf(e6, e7);                             \
      pa[q2] = cv.v;                                                            \
    }                                                                           \
    bf16x8 Vf[4];                                                               \
    Vf[0] = *(const bf16x8*)&Vs[offV];                                          \
    Vf[1] = *(const bf16x8*)&Vs[offV + 512];                                    \
    Vf[2] = *(const bf16x8*)&Vs[offV + 1024];                                   \
    Vf[3] = *(const bf16x8*)&Vs[offV + 1536];                                   \
    Lacc[0] = MFMA16(pa[0], vone, Lacc[0]);                                     \
    Lacc[1] = MFMA16(pa[1], vone, Lacc[1]);                                     \
    Lacc[2] = MFMA16(pa[2], vone, Lacc[2]);                                     \
    Lacc[3] = MFMA16(pa[3], vone, Lacc[3]);                                     \
    _Pragma("unroll") for (int q2 = 0; q2 < 4; q2++)                            \
      _Pragma("unroll") for (int dt = 0; dt < 4; dt++)                          \
        O[q2][dt] = MFMA16(pa[q2], Vf[dt], O[q2][dt]);                          \
  }

  // prologue: tile 0 in flight
  STAGE(0)
  // 32 iters: pairs with prefetch, then last tile without
  for (int t2 = 0; t2 < 15; t2++) {
    ITER(0, 1)
    ITER(1, 1)
  }
  ITER(0, 1)
  ITER(1, 0)
#undef ITER
#undef STAGE

  // ---- epilogue: combine the two waves' partials through LDS ----
  __syncthreads();
  float* CmbO = (float*)&KL[0][0][0];   // 16 KB: [64 q][64 d] f32 (wave-1)
  if (w == 1) {
#pragma unroll
    for (int q2 = 0; q2 < 4; q2++) {
      if (c == 0)
        *(f32x4*)&CL[q2 * 16 + quad * 4] = Lacc[q2];
#pragma unroll
      for (int dt = 0; dt < 4; dt++)
#pragma unroll
        for (int j = 0; j < 4; j++)
          CmbO[(q2 * 16 + quad * 4 + j) * 64 + dt * 16 + c] = O[q2][dt][j];
    }
  }
  __syncthreads();
  if (w == 0) {
    int b_ = bh >> 4, h = bh & 15;
#pragma unroll
    for (int q2 = 0; q2 < 4; q2++) {
#pragma unroll
      for (int j = 0; j < 4; j++) {
        int qrow = q2 * 16 + quad * 4 + j;
        float ltot = Lacc[q2][j] + CL[qrow];
        float linv = 1.0f / ltot;
        int n = qt * 64 + qrow;
        u16* op = ot + (((size_t)b_ * 2048 + n) * 16 + h) * 64;
#pragma unroll
        for (int dt = 0; dt < 4; dt++) {
          float o = O[q2][dt][j] + CmbO[qrow * 64 + dt * 16 + c];
          op[dt * 16 + c] = f2bf(o * linv);
        }
      }
    }
  }
}

// ---------------- output projection GEMM (bf16 A, fp32 W cast fused) -------
// A (attn out, bf16) reg-staged as uint4; B (wo, fp32) reg-staged + cvt.
// Same loop scheme as gemm_qkv. fp32 out.
__global__ __launch_bounds__(256) void gemm_out(
    const u16* __restrict__ Aot, const float* __restrict__ wo,
    const float* __restrict__ bo, float* __restrict__ out)
{
  __shared__ u16 As[64 * 64];
  __shared__ u16 Bs[128 * 64];
  int tid = threadIdx.x, w = tid >> 6, lane = tid & 63;
  int bm = blockIdx.x, bn = blockIdx.y;
  int wm = w >> 1, wn = w & 1;
  f32x4 acc[2][4] = {};
  uint4 rA[2];
  float4 rb[4][2];

#define OLOAD(K0)                                                               \
  {                                                                             \
    _Pragma("unroll") for (int i = 0; i < 2; i++) {                             \
      int seg = i * 256 + tid;                                                  \
      int row = seg >> 3, pseg = seg & 7;                                       \
      int lseg = pseg ^ (row & 7);                                              \
      rA[i] = *(const uint4*)(Aot + (size_t)(bm * 64 + row) * 1024 + (K0) + lseg * 8); \
    }                                                                           \
    _Pragma("unroll") for (int i = 0; i < 4; i++) {                             \
      int seg = i * 256 + tid;                                                  \
      int row = seg >> 3, pseg = seg & 7;                                       \
      int lseg = pseg ^ (row & 7);                                              \
      const float* pb = wo + (size_t)(bn * 128 + row) * 1024 + (K0) + lseg * 8; \
      rb[i][0] = *(const float4*)pb; rb[i][1] = *(const float4*)(pb + 4);       \
    }                                                                           \
  }

#define OWRITE                                                                  \
  {                                                                             \
    _Pragma("unroll") for (int i = 0; i < 2; i++) {                             \
      int seg = i * 256 + tid;                                                  \
      *(uint4*)&As[seg * 8] = rA[i];                                            \
    }                                                                           \
    _Pragma("unroll") for (int i = 0; i < 4; i++) {                             \
      int seg = i * 256 + tid;                                                  \
      uint4 wb;                                                                 \
      wb.x = pkbf(rb[i][0].x, rb[i][0].y); wb.y = pkbf(rb[i][0].z, rb[i][0].w); \
      wb.z = pkbf(rb[i][1].x, rb[i][1].y); wb.w = pkbf(rb[i][1].z, rb[i][1].w); \
      *(uint4*)&Bs[seg * 8] = wb;                                               \
    }                                                                           \
  }

#define OCOMP                                                                   \
  {                                                                             \
    _Pragma("unroll") for (int ks = 0; ks < 2; ks++) {                          \
      bf16x8 af[2], bfr[4];                                                     \
      _Pragma("unroll") for (int mt = 0; mt < 2; mt++) {                        \
        int row = wm * 32 + mt * 16 + (lane & 15);                              \
        int cseg = (ks * 4 + (lane >> 4)) ^ (row & 7);                          \
        af[mt] = *(const bf16x8*)&As[(row * 8 + cseg) * 8];                     \
      }                                                                         \
      _Pragma("unroll") for (int nt = 0; nt < 4; nt++) {                        \
        int row = wn * 64 + nt * 16 + (lane & 15);                              \
        int cseg = (ks * 4 + (lane >> 4)) ^ (row & 7);                          \
        bfr[nt] = *(const bf16x8*)&Bs[(row * 8 + cseg) * 8];                    \
      }                                                                         \
      _Pragma("unroll") for (int mt = 0; mt < 2; mt++)                          \
        _Pragma("unroll") for (int nt = 0; nt < 4; nt++)                        \
          acc[mt][nt] = MFMA16(af[mt], bfr[nt], acc[mt][nt]);                   \
    }                                                                           \
  }

  OLOAD(0)
  for (int st = 0; st < 16; st++) {
    OWRITE
    if (st < 15) OLOAD((st + 1) * 64)
    SB asm volatile("s_waitcnt lgkmcnt(0)" ::: "memory"); SB
    __builtin_amdgcn_s_barrier(); SB
    OCOMP
    SB __builtin_amdgcn_s_barrier(); SB
  }
#undef OCOMP
#undef OWRITE
#undef OLOAD

#pragma unroll
  for (int nt = 0; nt < 4; nt++) {
    int o = bn * 128 + wn * 64 + nt * 16 + (lane & 15);
    float bval = bo[o];
#pragma unroll
    for (int mt = 0; mt < 2; mt++)
#pragma unroll
      for (int j = 0; j < 4; j++) {
        int m = bm * 64 + wm * 32 + mt * 16 + (lane >> 4) * 4 + j;
        out[(size_t)m * 1024 + o] = acc[mt][nt][j] + bval;
      }
  }
}

extern "C" void kernel_launch(void* const* d_in, const int* in_sizes, int n_in,
                              void* d_out, int out_size, void* d_ws, size_t ws_size,
                              hipStream_t stream)
{
  const float* x  = (const float*)d_in[0];
  const float* qu = (const float*)d_in[1];
  const float* wq = (const float*)d_in[2];
  const float* bq = (const float*)d_in[3];
  const float* wk = (const float*)d_in[4];
  const float* bk = (const float*)d_in[5];
  const float* wv = (const float*)d_in[6];
  const float* bv = (const float*)d_in[7];
  const float* wo = (const float*)d_in[8];
  const float* bo = (const float*)d_in[9];
  float* out = (float*)d_out;
  char* ws = (char*)d_ws;
  u16* qhd = (u16*)(ws + (size_t)0);          // 8 MB  Q-scaled [B,H,N,D]
  u16* khd = (u16*)(ws + ((size_t)8  << 20)); // 8 MB  K [B,H,N,D]
  u16* vtd = (u16*)(ws + ((size_t)16 << 20)); // 8 MB  V^T permuted [B,H,D,N']
  u16* otd = (u16*)(ws + ((size_t)24 << 20)); // 8 MB  attn out [B,N,H,D]

  gemm_qkv<<<dim3(32, 8, 3), 256, 0, stream>>>(qu, x, wq, wk, wv,
                                               bq, bk, bv, qhd, khd, vtd);
  attn<<<dim3(32, 32), 128, 0, stream>>>(qhd, khd, vtd, otd);
  gemm_out<<<dim3(64, 8), 256, 0, stream>>>(otd, wo, bo, out);
}

// Round 12
// 201.438 us; speedup vs baseline: 1.1008x; 1.1008x over previous
//
#include <hip/hip_runtime.h>
#include <hip/hip_bf16.h>

typedef __attribute__((ext_vector_type(8))) short bf16x8;
typedef __attribute__((ext_vector_type(4))) float f32x4;
typedef unsigned short u16;
typedef unsigned int u32;

#define MFMA16(a,b,c) __builtin_amdgcn_mfma_f32_16x16x32_bf16((a),(b),(c),0,0,0)

#if defined(__has_builtin) && __has_builtin(__builtin_amdgcn_exp2f)
#define EXP2(x) __builtin_amdgcn_exp2f(x)
#else
#define EXP2(x) exp2f(x)
#endif

// softmax scale folded into Q at projection time: (1/32) * log2(e)
#define QSCALE 0.045084220027780106f

__device__ __forceinline__ u16 f2bf(float f) {
  union { float f; unsigned int u; } v; v.f = f;
  unsigned int r = v.u + 0x7FFFu + ((v.u >> 16) & 1u);   // RNE
  return (u16)(r >> 16);
}

__device__ __forceinline__ u32 pkbf(float a, float b) {
  union { __hip_bfloat162 h; u32 u; } cv;
  cv.h = __float22bfloat162_rn(make_float2(a, b));
  return cv.u;
}

// async global->LDS, 16B per lane; LDS dest = wave-uniform base + lane*16
__device__ __forceinline__ void gld16(const void* g, void* l) {
  __builtin_amdgcn_global_load_lds(
      (__attribute__((address_space(1))) void*)(g),
      (__attribute__((address_space(3))) void*)(l), 16, 0, 0);
}

// ---------------- cast fp32 -> bf16 (all inputs, one launch) ----------------
__global__ __launch_bounds__(256) void cast_all(
    const float* __restrict__ x, const float* __restrict__ qu,
    const float* __restrict__ wq, const float* __restrict__ wk,
    const float* __restrict__ wv, const float* __restrict__ wo,
    u16* __restrict__ xb, u16* __restrict__ qub,
    u16* __restrict__ wqb, u16* __restrict__ wkb,
    u16* __restrict__ wvb, u16* __restrict__ wob)
{
  int i = blockIdx.x * 256 + threadIdx.x;   // float4 index
  const float4* src; u16* dst; int off;
  if (i < 1048576)      { src = (const float4*)qu; dst = qub; off = i; }
  else if (i < 2097152) { src = (const float4*)x;  dst = xb;  off = i - 1048576; }
  else if (i < 2359296) { src = (const float4*)wq; dst = wqb; off = i - 2097152; }
  else if (i < 2621440) { src = (const float4*)wk; dst = wkb; off = i - 2359296; }
  else if (i < 2883584) { src = (const float4*)wv; dst = wvb; off = i - 2621440; }
  else                  { src = (const float4*)wo; dst = wob; off = i - 2883584; }
  float4 v = src[off];
  ushort4 r; r.x = f2bf(v.x); r.y = f2bf(v.y); r.z = f2bf(v.z); r.w = f2bf(v.w);
  ((ushort4*)dst)[off] = r;
}

// ---------------- fused QKV projection GEMM ----------------
// z=0: Q*(scale*log2e) -> [B,H,N,D]; z=1: K -> [B,H,N,D]  — computed as C^T
//      (swap MFMA operands) so each lane holds 4 consecutive channels ->
//      packed 8-B stores, no LDS transpose.
// z=2: V -> [B,H,D,N'] — normal orientation: lane j-values are 4 consecutive
//      permuted tokens (k' = (mt&2)*16 + quad*8 + (mt&1)*4 + j) -> packed
//      8-B stores directly into the transposed layout.
__global__ __launch_bounds__(256) void gemm_qkv(
    const u16* __restrict__ qub, const u16* __restrict__ xb,
    const u16* __restrict__ wqb, const u16* __restrict__ wkb, const u16* __restrict__ wvb,
    const float* __restrict__ bq, const float* __restrict__ bk, const float* __restrict__ bv,
    u16* __restrict__ qhd, u16* __restrict__ khd, u16* __restrict__ vtd)
{
  __shared__ u16 As[128 * 64];
  __shared__ u16 Bs[128 * 64];
  int tid = threadIdx.x, w = tid >> 6, lane = tid & 63;
  int c = lane & 15, quad = lane >> 4;
  int bm = blockIdx.x, bn = blockIdx.y, z = blockIdx.z;
  int wm = w >> 1, wn = w & 1;
  const u16* A = (z == 0) ? qub : xb;
  const u16* W = (z == 0) ? wqb : (z == 1) ? wkb : wvb;
  f32x4 acc[4][4] = {};
  for (int k0 = 0; k0 < 1024; k0 += 64) {
#pragma unroll
    for (int i = 0; i < 4; i++) {
      int seg = i * 256 + w * 64 + lane;          // physical 8-elem segment
      int row = seg >> 3, pseg = seg & 7;
      int lseg = pseg ^ (row & 7);                // logical k-segment (XOR swizzle)
      gld16(A + (size_t)(bm * 128 + row) * 1024 + k0 + lseg * 8,
            &As[(i * 256 + w * 64) * 8]);
      gld16(W + (size_t)(bn * 128 + row) * 1024 + k0 + lseg * 8,
            &Bs[(i * 256 + w * 64) * 8]);
    }
    __syncthreads();
#pragma unroll
    for (int ks = 0; ks < 2; ks++) {
      bf16x8 af[4], bfr[4];
#pragma unroll
      for (int mt = 0; mt < 4; mt++) {
        int row = wm * 64 + mt * 16 + c;
        int cseg = (ks * 4 + quad) ^ (row & 7);
        af[mt] = *(const bf16x8*)&As[(row * 8 + cseg) * 8];
      }
#pragma unroll
      for (int nt = 0; nt < 4; nt++) {
        int row = wn * 64 + nt * 16 + c;
        int cseg = (ks * 4 + quad) ^ (row & 7);
        bfr[nt] = *(const bf16x8*)&Bs[(row * 8 + cseg) * 8];
      }
      if (z < 2) {
        // C^T: rows = channels (W frags as A-operand), cols = tokens
#pragma unroll
        for (int ct = 0; ct < 4; ct++)
#pragma unroll
          for (int tt = 0; tt < 4; tt++)
            acc[ct][tt] = MFMA16(bfr[ct], af[tt], acc[ct][tt]);
      } else {
#pragma unroll
        for (int mt = 0; mt < 4; mt++)
#pragma unroll
          for (int nt = 0; nt < 4; nt++)
            acc[mt][nt] = MFMA16(af[mt], bfr[nt], acc[mt][nt]);
      }
    }
    __syncthreads();
  }
  if (z < 2) {
    const float* bias = (z == 0) ? bq : bk;
    u16* dst = (z == 0) ? qhd : khd;
    float sc = (z == 0) ? QSCALE : 1.0f;
    // per-lane bias for 4 consecutive channels per ct (16B-aligned)
    float4 bbs[4];
#pragma unroll
    for (int ct = 0; ct < 4; ct++) {
      float4 b4 = *(const float4*)&bias[bn * 128 + wn * 64 + ct * 16 + quad * 4];
      bbs[ct].x = b4.x * sc; bbs[ct].y = b4.y * sc;
      bbs[ct].z = b4.z * sc; bbs[ct].w = b4.w * sc;
    }
#pragma unroll
    for (int ct = 0; ct < 4; ct++) {
      int ch = bn * 128 + wn * 64 + ct * 16 + quad * 4;
      int h = ch >> 6, d0 = ch & 63;
#pragma unroll
      for (int tt = 0; tt < 4; tt++) {
        int tok = bm * 128 + wm * 64 + tt * 16 + c;
        int b = tok >> 11, n = tok & 2047;
        float v0 = fmaf(acc[ct][tt][0], sc, bbs[ct].x);
        float v1 = fmaf(acc[ct][tt][1], sc, bbs[ct].y);
        float v2 = fmaf(acc[ct][tt][2], sc, bbs[ct].z);
        float v3 = fmaf(acc[ct][tt][3], sc, bbs[ct].w);
        uint2 pk; pk.x = pkbf(v0, v1); pk.y = pkbf(v2, v3);
        *(uint2*)&dst[((size_t)(b * 16 + h) * 2048 + n) * 64 + d0] = pk;
      }
    }
  } else {
    float bval[4];
#pragma unroll
    for (int nt = 0; nt < 4; nt++)
      bval[nt] = bv[bn * 128 + wn * 64 + nt * 16 + c];
#pragma unroll
    for (int mt = 0; mt < 4; mt++) {
      int tokl = (mt & 2) * 16 + quad * 8 + (mt & 1) * 4;   // permuted, +j
      int tok = bm * 128 + wm * 64 + tokl;
      int b = tok >> 11, np = tok & 2047;
#pragma unroll
      for (int nt = 0; nt < 4; nt++) {
        int ch = bn * 128 + wn * 64 + nt * 16 + c;
        int h = ch >> 6, d = ch & 63;
        float v0 = acc[mt][nt][0] + bval[nt];
        float v1 = acc[mt][nt][1] + bval[nt];
        float v2 = acc[mt][nt][2] + bval[nt];
        float v3 = acc[mt][nt][3] + bval[nt];
        uint2 pk; pk.x = pkbf(v0, v1); pk.y = pkbf(v2, v3);
        *(uint2*)&vtd[((size_t)(b * 16 + h) * 64 + d) * 2048 + np] = pk;
      }
    }
  }
}

// ---------------- attention v14: v12 + conflict-free packed V tile --------
// grid (32 bh, 32 qt), block = 128 thr (2 waves). Block owns a 64-q tile;
// wave w sweeps tokens [w*1024, w*1024+1024) in 32 tiles of 32 with a
// PRIVATE double-buffer. NEW vs v12: V tile packs TWO d-rows per 128-B LDS
// row ([32 rows][64 elems]: row r = {d=2r: tok' 0..31 | d=2r+1: tok' 0..31})
// with full 3-bit XOR swizzle slot' = slot ^ (row&7) -- same conflict-free
// structure as the K tile. v12's 64-B V rows forced even/odd-lane bank
// halving (1.31M conflicts/dispatch); 128-B rows restore the full spread.
// Same STAGE shape (4 gld16, +32768 strides); only per-lane source base and
// the offV read formula change. Lane->element semantics unchanged.
__global__ __launch_bounds__(128, 2) void attn(
    const u16* __restrict__ qh, const u16* __restrict__ kh,
    const u16* __restrict__ vt, u16* __restrict__ ot)
{
  __shared__ u16 KL[2][2][32 * 64];   // [wave][buf] K tile [32 tok][64 d], 4 KB
  __shared__ u16 VL[2][2][32 * 64];   // [wave][buf] V packed [32 rows][64], 4 KB
  __shared__ float CL[64];            // wave-1 L partials
  int tid = threadIdx.x, w = tid >> 6, lane = tid & 63;
  int c = lane & 15, quad = lane >> 4;
  int bh = blockIdx.x, qt = blockIdx.y;

  // Q B-frags in registers: 64 q shared by both waves
  const u16* qp = qh + ((size_t)bh * 2048 + qt * 64) * 64;
  bf16x8 Qf[4][2];
#pragma unroll
  for (int q2 = 0; q2 < 4; q2++)
#pragma unroll
    for (int ks = 0; ks < 2; ks++)
      Qf[q2][ks] = *(const bf16x8*)(qp + (size_t)(q2 * 16 + c) * 64 + ks * 32 + quad * 8);

  // K staging: 4 loads; load i covers token-row i*8+(lane>>3), seg (lane&7)^(row&7)
  int kro = lane >> 3;                    // 0..7
  int ksw = ((lane & 7) ^ (kro & 7)) * 8;
  const u16* kg = kh + (size_t)bh * 131072 + (size_t)w * 65536 + kro * 64 + ksw;
  // V staging (packed rows): load i covers packed-row i*8+(lane>>3);
  // physical slot' = lane&7, source slot = slot'^(row&7) = (lane&7)^(lane>>3);
  // slot encodes d&1 = slot>>2 and tok' chunk = (slot&3)*8.
  int vrow = lane >> 3;                   // 0..7
  int vslot = (lane & 7) ^ vrow;          // unswizzled source slot
  int vdb = 2 * vrow + (vslot >> 2);      // source d within 16-row group
  int vto = (vslot & 3) * 8;              // source tok' offset
  const u16* vg = vt + (size_t)bh * 131072 + (size_t)vdb * 2048 + w * 1024 + vto;

  // fragment read offsets (swizzled)
  int off0 = c * 64 + ((quad) ^ (c & 7)) * 8;        // K ks=0 (d 0..31)
  int off1 = c * 64 + ((4 + quad) ^ (c & 7)) * 8;    // K ks=1 (d 32..63)
  // V: d = dt*16+c -> packed row dt*8+(c>>1), slot = (c&1)*4+quad,
  //    slot' = slot ^ (row&7) with row&7 = c>>1
  int offV = (c >> 1) * 64 + ((((c & 1) << 2) + quad) ^ (c >> 1)) * 8;  // + dt*512

#define STAGE(B)                                                                \
  {                                                                             \
    gld16(kg,          &KL[w][B][0]);                                           \
    gld16(kg + 512,    &KL[w][B][512]);                                         \
    gld16(kg + 1024,   &KL[w][B][1024]);                                        \
    gld16(kg + 1536,   &KL[w][B][1536]);                                        \
    gld16(vg,          &VL[w][B][0]);                                           \
    gld16(vg + 32768,  &VL[w][B][512]);                                         \
    gld16(vg + 65536,  &VL[w][B][1024]);                                        \
    gld16(vg + 98304,  &VL[w][B][1536]);                                        \
    kg += 2048; vg += 32;                                                       \
  }

  f32x4 O[4][4] = {};
  f32x4 Lacc[4] = {};
  bf16x8 vone;
#pragma unroll
  for (int j = 0; j < 8; j++) vone[j] = (short)0x3F80;   // bf16 1.0

  // per iter: [lgkm(0)] protect buf about to be overwritten; stage t+1;
  // counted vmcnt(8) -> tile t's 8 loads complete; compute tile t.
#define ITER(PH, PREF)                                                          \
  {                                                                             \
    asm volatile("s_waitcnt lgkmcnt(0)" ::: "memory");                          \
    __builtin_amdgcn_sched_barrier(0);                                          \
    if (PREF) STAGE(PH ^ 1)                                                     \
    if (PREF) { asm volatile("s_waitcnt vmcnt(8)" ::: "memory"); }              \
    else      { asm volatile("s_waitcnt vmcnt(0)" ::: "memory"); }              \
    __builtin_amdgcn_sched_barrier(0);                                          \
    const u16* Ks = KL[w][PH];                                                  \
    const u16* Vs = VL[w][PH];                                                  \
    bf16x8 Kf[2][2];                                                            \
    Kf[0][0] = *(const bf16x8*)&Ks[off0];                                       \
    Kf[0][1] = *(const bf16x8*)&Ks[off1];                                       \
    Kf[1][0] = *(const bf16x8*)&Ks[off0 + 1024];                                \
    Kf[1][1] = *(const bf16x8*)&Ks[off1 + 1024];                                \
    f32x4 S[4][2] = {};                                                         \
    _Pragma("unroll") for (int q2 = 0; q2 < 4; q2++)                            \
      _Pragma("unroll") for (int nt = 0; nt < 2; nt++) {                        \
        S[q2][nt] = MFMA16(Kf[nt][0], Qf[q2][0], S[q2][nt]);                    \
        S[q2][nt] = MFMA16(Kf[nt][1], Qf[q2][1], S[q2][nt]);                    \
      }                                                                         \
    bf16x8 pa[4];                                                               \
    _Pragma("unroll") for (int q2 = 0; q2 < 4; q2++) {                          \
      float e0 = EXP2(S[q2][0][0]), e1 = EXP2(S[q2][0][1]);                     \
      float e2 = EXP2(S[q2][0][2]), e3 = EXP2(S[q2][0][3]);                     \
      float e4 = EXP2(S[q2][1][0]), e5 = EXP2(S[q2][1][1]);                     \
      float e6 = EXP2(S[q2][1][2]), e7 = EXP2(S[q2][1][3]);                     \
      union { uint4 u; bf16x8 v; } cv;                                          \
      cv.u.x = pkbf(e0, e1); cv.u.y = pkbf(e2, e3);                             \
      cv.u.z = pkbf(e4, e5); cv.u.w = pkbf(e6, e7);                             \
      pa[q2] = cv.v;                                                            \
    }                                                                           \
    bf16x8 Vf[4];                                                               \
    Vf[0] = *(const bf16x8*)&Vs[offV];                                          \
    Vf[1] = *(const bf16x8*)&Vs[offV + 512];                                    \
    Vf[2] = *(const bf16x8*)&Vs[offV + 1024];                                   \
    Vf[3] = *(const bf16x8*)&Vs[offV + 1536];                                   \
    Lacc[0] = MFMA16(pa[0], vone, Lacc[0]);                                     \
    Lacc[1] = MFMA16(pa[1], vone, Lacc[1]);                                     \
    Lacc[2] = MFMA16(pa[2], vone, Lacc[2]);                                     \
    Lacc[3] = MFMA16(pa[3], vone, Lacc[3]);                                     \
    _Pragma("unroll") for (int q2 = 0; q2 < 4; q2++)                            \
      _Pragma("unroll") for (int dt = 0; dt < 4; dt++)                          \
        O[q2][dt] = MFMA16(pa[q2], Vf[dt], O[q2][dt]);                          \
  }

  // prologue: tile 0 in flight
  STAGE(0)
  // 32 iters: pairs with prefetch, then last tile without
  for (int t2 = 0; t2 < 15; t2++) {
    ITER(0, 1)
    ITER(1, 1)
  }
  ITER(0, 1)
  ITER(1, 0)
#undef ITER
#undef STAGE

  // ---- epilogue: combine the two waves' partials through LDS ----
  __syncthreads();
  float* CmbO = (float*)&KL[0][0][0];   // 16 KB: [64 q][64 d] f32 (wave-1)
  if (w == 1) {
#pragma unroll
    for (int q2 = 0; q2 < 4; q2++) {
      if (c == 0)
        *(f32x4*)&CL[q2 * 16 + quad * 4] = Lacc[q2];
#pragma unroll
      for (int dt = 0; dt < 4; dt++)
#pragma unroll
        for (int j = 0; j < 4; j++)
          CmbO[(q2 * 16 + quad * 4 + j) * 64 + dt * 16 + c] = O[q2][dt][j];
    }
  }
  __syncthreads();
  if (w == 0) {
    int b_ = bh >> 4, h = bh & 15;
#pragma unroll
    for (int q2 = 0; q2 < 4; q2++) {
#pragma unroll
      for (int j = 0; j < 4; j++) {
        int qrow = q2 * 16 + quad * 4 + j;
        float ltot = Lacc[q2][j] + CL[qrow];
        float linv = 1.0f / ltot;
        int n = qt * 64 + qrow;
        u16* op = ot + (((size_t)b_ * 2048 + n) * 16 + h) * 64;
#pragma unroll
        for (int dt = 0; dt < 4; dt++) {
          float o = O[q2][dt][j] + CmbO[qrow * 64 + dt * 16 + c];
          op[dt * 16 + c] = f2bf(o * linv);
        }
      }
    }
  }
}

// ---------------- output projection GEMM (fp32 out), 64x128 tile ----------
__global__ __launch_bounds__(256) void gemm_out(
    const u16* __restrict__ Aot, const u16* __restrict__ wob,
    const float* __restrict__ bo, float* __restrict__ out)
{
  __shared__ u16 As[64 * 64];
  __shared__ u16 Bs[128 * 64];
  int tid = threadIdx.x, w = tid >> 6, lane = tid & 63;
  int bm = blockIdx.x, bn = blockIdx.y;
  int wm = w >> 1, wn = w & 1;
  f32x4 acc[2][4] = {};
  for (int k0 = 0; k0 < 1024; k0 += 64) {
#pragma unroll
    for (int i = 0; i < 2; i++) {
      int seg = i * 256 + tid;
      int row = seg >> 3, pseg = seg & 7;
      int lseg = pseg ^ (row & 7);
      gld16(Aot + (size_t)(bm * 64 + row) * 1024 + k0 + lseg * 8,
            &As[(i * 256 + tid - (tid & 7)) * 8 + (tid & 7) * 8]);
    }
#pragma unroll
    for (int i = 0; i < 4; i++) {
      int seg = i * 256 + tid;
      int row = seg >> 3, pseg = seg & 7;
      int lseg = pseg ^ (row & 7);
      gld16(wob + (size_t)(bn * 128 + row) * 1024 + k0 + lseg * 8,
            &Bs[(i * 256 + tid - (tid & 7)) * 8 + (tid & 7) * 8]);
    }
    __syncthreads();
#pragma unroll
    for (int ks = 0; ks < 2; ks++) {
      bf16x8 af[2], bfr[4];
#pragma unroll
      for (int mt = 0; mt < 2; mt++) {
        int row = wm * 32 + mt * 16 + (lane & 15);
        int cseg = (ks * 4 + (lane >> 4)) ^ (row & 7);
        af[mt] = *(const bf16x8*)&As[(row * 8 + cseg) * 8];
      }
#pragma unroll
      for (int nt = 0; nt < 4; nt++) {
        int row = wn * 64 + nt * 16 + (lane & 15);
        int cseg = (ks * 4 + (lane >> 4)) ^ (row & 7);
        bfr[nt] = *(const bf16x8*)&Bs[(row * 8 + cseg) * 8];
      }
#pragma unroll
      for (int mt = 0; mt < 2; mt++)
#pragma unroll
        for (int nt = 0; nt < 4; nt++)
          acc[mt][nt] = MFMA16(af[mt], bfr[nt], acc[mt][nt]);
    }
    __syncthreads();
  }
#pragma unroll
  for (int nt = 0; nt < 4; nt++) {
    int o = bn * 128 + wn * 64 + nt * 16 + (lane & 15);
    float bval = bo[o];
#pragma unroll
    for (int mt = 0; mt < 2; mt++)
#pragma unroll
      for (int j = 0; j < 4; j++) {
        int m = bm * 64 + wm * 32 + mt * 16 + (lane >> 4) * 4 + j;
        out[(size_t)m * 1024 + o] = acc[mt][nt][j] + bval;
      }
  }
}

extern "C" void kernel_launch(void* const* d_in, const int* in_sizes, int n_in,
                              void* d_out, int out_size, void* d_ws, size_t ws_size,
                              hipStream_t stream)
{
  const float* x  = (const float*)d_in[0];
  const float* qu = (const float*)d_in[1];
  const float* wq = (const float*)d_in[2];
  const float* bq = (const float*)d_in[3];
  const float* wk = (const float*)d_in[4];
  const float* bk = (const float*)d_in[5];
  const float* wv = (const float*)d_in[6];
  const float* bv = (const float*)d_in[7];
  const float* wo = (const float*)d_in[8];
  const float* bo = (const float*)d_in[9];
  float* out = (float*)d_out;
  char* ws = (char*)d_ws;
  u16* xb  = (u16*)(ws + (size_t)0);          // 8 MB
  u16* qub = (u16*)(ws + ((size_t)8  << 20)); // 8 MB
  u16* wqb = (u16*)(ws + ((size_t)16 << 20)); // 2 MB
  u16* wkb = (u16*)(ws + ((size_t)18 << 20)); // 2 MB
  u16* wvb = (u16*)(ws + ((size_t)20 << 20)); // 2 MB
  u16* wob = (u16*)(ws + ((size_t)22 << 20)); // 2 MB
  u16* qhd = (u16*)(ws + ((size_t)24 << 20)); // 8 MB  Q-scaled [B,H,N,D]
  u16* khd = (u16*)(ws + ((size_t)32 << 20)); // 8 MB  K [B,H,N,D]
  u16* vtd = (u16*)(ws + ((size_t)40 << 20)); // 8 MB  V^T permuted [B,H,D,N']
  u16* otd = (u16*)(ws + ((size_t)48 << 20)); // 8 MB  attn out [B,N,H,D]

  cast_all<<<12288, 256, 0, stream>>>(x, qu, wq, wk, wv, wo,
                                      xb, qub, wqb, wkb, wvb, wob);
  gemm_qkv<<<dim3(32, 8, 3), 256, 0, stream>>>(qub, xb, wqb, wkb, wvb,
                                               bq, bk, bv, qhd, khd, vtd);
  attn<<<dim3(32, 32), 128, 0, stream>>>(qhd, khd, vtd, otd);
  gemm_out<<<dim3(64, 8), 256, 0, stream>>>(otd, wob, bo, out);
}